// Round 7
// baseline (194.817 us; speedup 1.0000x reference)
//
#include <hip/hip_runtime.h>
#include <hip/hip_bf16.h>
#include <float.h>

// Problem constants
#define B_   8
#define T_   2048
#define CIN  1024      // INPUT_DIM
#define DD   8         // CODEBOOK_DIM
#define KC   8192      // CODEBOOK_SIZE
#define NTOK (B_*T_)   // 16384 tokens
#define NSLICE 16
#define SLICE (KC/NSLICE)   // 512 codes per slice

// d_out layout, ALL float32 (harness reads whole buffer as the ref output dtype):
//   out[B,CIN,T] | indices[B,T] (as float values!) | z_e[B,DD,T]
#define IDX_OFF ((size_t)B_*CIN*T_)       // 16777216
#define ZE_OFF  (IDX_OFF + NTOK)          // 16793600

// ws layout (float units)
#define WS_ENCN  0                         // 131072: normalized enc [16384][8]
#define WS_SE    (WS_ENCN + NTOK*DD)       // 16384 : sum(enc_n^2) per token
#define WS_PDIST (WS_SE + NTOK)            // 262144: partial best dist [16][16384]
#define WS_PIDX  (WS_PDIST + NSLICE*NTOK)  // 262144: partial best idx  [16][16384]
// total = 671744 floats = 2.56 MiB of ws

// ---------------- Kernel 1: in-projection + normalize enc ----------------
// grid = 512 blocks (NTOK/32), block = 256 threads = 8 c-groups x 32 tokens
__global__ __launch_bounds__(256) void inproj(const float* __restrict__ z,
                                              const float* __restrict__ W_in,
                                              const float* __restrict__ b_in,
                                              float* __restrict__ out,
                                              float* __restrict__ ws) {
    __shared__ float wt[CIN * DD];        // W_in transposed to [c][d], 32 KiB
    __shared__ float red[8][32][DD];      // partial sums, 8 KiB
    int tid = threadIdx.x;
    // coalesced load of W_in [8][1024], transposed store into wt[c*8+d]
    for (int idx = tid; idx < CIN * DD; idx += 256) {
        int d = idx >> 10, c = idx & 1023;
        wt[c * 8 + d] = W_in[idx];
    }
    __syncthreads();

    int bid = blockIdx.x;
    int b  = bid >> 6;        // 64 token-groups of 32 per batch
    int tg = bid & 63;
    int t0 = tg * 32;
    int g = tid >> 5, tl = tid & 31;   // 8 c-groups x 32 tokens

    const float* zp = z + ((size_t)b * CIN) * T_ + (t0 + tl);
    float acc[8] = {0, 0, 0, 0, 0, 0, 0, 0};
    int cbeg = g * 128;
    #pragma unroll 8
    for (int c = cbeg; c < cbeg + 128; ++c) {
        float v = zp[(size_t)c * T_];
        const float4* w4 = (const float4*)&wt[c * DD];
        float4 w0 = w4[0], w1 = w4[1];
        acc[0] = fmaf(w0.x, v, acc[0]);
        acc[1] = fmaf(w0.y, v, acc[1]);
        acc[2] = fmaf(w0.z, v, acc[2]);
        acc[3] = fmaf(w0.w, v, acc[3]);
        acc[4] = fmaf(w1.x, v, acc[4]);
        acc[5] = fmaf(w1.y, v, acc[5]);
        acc[6] = fmaf(w1.z, v, acc[6]);
        acc[7] = fmaf(w1.w, v, acc[7]);
    }
    #pragma unroll
    for (int d = 0; d < 8; ++d) red[g][tl][d] = acc[d];
    __syncthreads();

    if (tid < 32) {
        int tt = tid;
        float ze[8];
        #pragma unroll
        for (int d = 0; d < 8; ++d) {
            float s01 = (red[0][tt][d] + red[1][tt][d]) + (red[2][tt][d] + red[3][tt][d]);
            float s23 = (red[4][tt][d] + red[5][tt][d]) + (red[6][tt][d] + red[7][tt][d]);
            ze[d] = (s01 + s23) + b_in[d];
        }
        // write z_e [B, 8, T]
        float* zeo = out + ZE_OFF + ((size_t)b * DD) * T_ + (t0 + tt);
        #pragma unroll
        for (int d = 0; d < 8; ++d) zeo[(size_t)d * T_] = ze[d];
        // normalize, matching XLA rounding: squares rounded individually (mul HLO),
        // then sequential reduce-add (reduce HLO). No fma contraction.
        float s2 = __fmul_rn(ze[0], ze[0]);
        #pragma unroll
        for (int d = 1; d < 8; ++d) s2 = __fadd_rn(s2, __fmul_rn(ze[d], ze[d]));
        float m = fmaxf(sqrtf(s2), 1e-12f);
        float en[8];
        #pragma unroll
        for (int d = 0; d < 8; ++d) en[d] = ze[d] / m;
        float se = __fmul_rn(en[0], en[0]);
        #pragma unroll
        for (int d = 1; d < 8; ++d) se = __fadd_rn(se, __fmul_rn(en[d], en[d]));
        int token = b * T_ + t0 + tt;
        float4* ep = (float4*)(ws + WS_ENCN + (size_t)token * DD);
        ep[0] = make_float4(en[0], en[1], en[2], en[3]);
        ep[1] = make_float4(en[4], en[5], en[6], en[7]);
        ws[WS_SE + token] = se;
    }
}

// ---------------- Kernel 2: codebook search (normalize fused, per slice) ----------------
// grid = 1024 blocks = 64 token-groups x 16 slices; block = 256 threads (1 token each)
__global__ __launch_bounds__(256) void vq_search(const float* __restrict__ cb,
                                                 float* __restrict__ ws) {
    __shared__ float lcb[SLICE * DD];   // 16 KiB, [j][k] contiguous (normalized)
    __shared__ float lsc[SLICE];        // 2 KiB  sum(cn^2)
    int tid = threadIdx.x;
    int bid = blockIdx.x;
    int sl = bid & (NSLICE - 1);
    int tg = bid >> 4;

    // stage + normalize 512 codes of this slice (2 codes/thread),
    // rounding matched to reference _l2norm / sum structure
    #pragma unroll
    for (int r = 0; r < 2; ++r) {
        int jl = tid + r * 256;
        const float4* src = (const float4*)(cb + (size_t)(sl * SLICE + jl) * DD);
        float4 a = src[0], bv = src[1];
        float c[8] = {a.x, a.y, a.z, a.w, bv.x, bv.y, bv.z, bv.w};
        float s2 = __fmul_rn(c[0], c[0]);
        #pragma unroll
        for (int k = 1; k < 8; ++k) s2 = __fadd_rn(s2, __fmul_rn(c[k], c[k]));
        float m = fmaxf(sqrtf(s2), 1e-12f);
        float cn[8];
        #pragma unroll
        for (int k = 0; k < 8; ++k) cn[k] = c[k] / m;
        float sc = __fmul_rn(cn[0], cn[0]);
        #pragma unroll
        for (int k = 1; k < 8; ++k) sc = __fadd_rn(sc, __fmul_rn(cn[k], cn[k]));
        float4* dst = (float4*)&lcb[jl * DD];
        dst[0] = make_float4(cn[0], cn[1], cn[2], cn[3]);
        dst[1] = make_float4(cn[4], cn[5], cn[6], cn[7]);
        lsc[jl] = sc;
    }
    __syncthreads();

    int token = tg * 256 + tid;
    const float4* ep4 = (const float4*)(ws + WS_ENCN + (size_t)token * DD);
    float4 ea = ep4[0], eb = ep4[1];
    float se = ws[WS_SE + token];

    float best = FLT_MAX;
    int bi = 0;
    // dist = (se - 2*dot) + sc. fmaf(-2,dot,se) is bit-identical to the
    // reference's mul-then-sub because *2 is exact; single rounding either way.
    #pragma unroll 8
    for (int j = 0; j < SLICE; ++j) {
        const float4* c4 = (const float4*)&lcb[j * DD];
        float4 ca = c4[0], cbv = c4[1];
        float dot = ea.x * ca.x;
        dot = fmaf(ea.y, ca.y, dot);
        dot = fmaf(ea.z, ca.z, dot);
        dot = fmaf(ea.w, ca.w, dot);
        dot = fmaf(eb.x, cbv.x, dot);
        dot = fmaf(eb.y, cbv.y, dot);
        dot = fmaf(eb.z, cbv.z, dot);
        dot = fmaf(eb.w, cbv.w, dot);
        float dist = __fadd_rn(fmaf(-2.f, dot, se), lsc[j]);
        bool p = dist < best;                       // strict <: first min wins (argmax of -dist)
        best = p ? dist : best;
        bi   = p ? j : bi;
    }
    ws[WS_PDIST + (size_t)sl * NTOK + token] = best;
    ((int*)ws)[WS_PIDX + (size_t)sl * NTOK + token] = sl * SLICE + bi;
}

// ---------------- Kernel 3: merge + indices + gather + STE + out-projection ----------------
// grid = B * 32 tgroups * 2 cgroups = 512 blocks; block = 4 c-lanes x 64 tokens
__global__ __launch_bounds__(256) void outproj(const float* __restrict__ ws,
                                               const float* __restrict__ cb,
                                               const float* __restrict__ W_out,
                                               const float* __restrict__ b_out,
                                               float* __restrict__ out) {
    __shared__ float zq[DD * 64];   // [d][t]
    int tid = threadIdx.x;
    int bid = blockIdx.x;
    int b   = bid >> 6;
    int rem = bid & 63;
    int tg  = rem >> 1;
    int cg  = rem & 1;
    int t0 = tg * 64;

    if (tid < 64) {
        int tl = tid;
        int token = b * T_ + t0 + tl;
        // merge 16 slice minima (strict <: earlier slice wins ties)
        float best = ws[WS_PDIST + token];
        int bi = ((const int*)ws)[WS_PIDX + token];
        #pragma unroll
        for (int s = 1; s < NSLICE; ++s) {
            float d = ws[WS_PDIST + (size_t)s * NTOK + token];
            int i2  = ((const int*)ws)[WS_PIDX + (size_t)s * NTOK + token];
            bool p = d < best;
            best = p ? d : best;
            bi   = p ? i2 : bi;
        }
        // write index AS A FLOAT VALUE (harness reads whole out buffer as f32);
        // duplicate identical writes across the 2 cg blocks are benign
        out[IDX_OFF + token] = (float)bi;
        // read back z_e, gather UNnormalized code, replicate STE rounding:
        // z_q_out = z_e + (z_q - z_e)  (elementwise fp32, as XLA computes it)
        const float* zep = out + ZE_OFF + ((size_t)b * DD) * T_ + (t0 + tl);
        const float4* cv4 = (const float4*)(cb + (size_t)bi * DD);
        float4 ca = cv4[0], cbv = cv4[1];
        float cv[8] = {ca.x, ca.y, ca.z, ca.w, cbv.x, cbv.y, cbv.z, cbv.w};
        #pragma unroll
        for (int d = 0; d < 8; ++d) {
            float ze = zep[(size_t)d * T_];
            zq[d * 64 + tl] = __fadd_rn(ze, __fsub_rn(cv[d], ze));
        }
    }
    __syncthreads();

    int cl = tid >> 6, tl = tid & 63;
    float q[8];
    #pragma unroll
    for (int k = 0; k < 8; ++k) q[k] = zq[k * 64 + tl];

    int cbase = cg * 512 + cl * 128;
    float* op = out + ((size_t)b * CIN) * T_ + (t0 + tl);
    #pragma unroll 4
    for (int i = 0; i < 128; ++i) {
        int c = cbase + i;
        const float4* w4 = (const float4*)(W_out + (size_t)c * DD);
        float4 w0 = w4[0], w1 = w4[1];
        float dot = q[0] * w0.x;
        dot = fmaf(q[1], w0.y, dot);
        dot = fmaf(q[2], w0.z, dot);
        dot = fmaf(q[3], w0.w, dot);
        dot = fmaf(q[4], w1.x, dot);
        dot = fmaf(q[5], w1.y, dot);
        dot = fmaf(q[6], w1.z, dot);
        dot = fmaf(q[7], w1.w, dot);
        op[(size_t)c * T_] = dot + b_out[c];
    }
}

extern "C" void kernel_launch(void* const* d_in, const int* in_sizes, int n_in,
                              void* d_out, int out_size, void* d_ws, size_t ws_size,
                              hipStream_t stream) {
    const float* z     = (const float*)d_in[0];
    const float* W_in  = (const float*)d_in[1];
    const float* b_in  = (const float*)d_in[2];
    const float* W_out = (const float*)d_in[3];
    const float* b_out = (const float*)d_in[4];
    const float* cb    = (const float*)d_in[5];
    float* out = (float*)d_out;
    float* ws  = (float*)d_ws;

    inproj<<<NTOK / 32, 256, 0, stream>>>(z, W_in, b_in, out, ws);
    vq_search<<<(NTOK / 256) * NSLICE, 256, 0, stream>>>(cb, ws);
    outproj<<<B_ * 32 * 2, 256, 0, stream>>>(ws, cb, W_out, b_out, out);
}

// Round 10
// 194.031 us; speedup vs baseline: 1.0041x; 1.0041x over previous
//
#include <hip/hip_runtime.h>
#include <float.h>

// Problem constants
#define B_   8
#define T_   2048
#define CIN  1024      // INPUT_DIM
#define DD   8         // CODEBOOK_DIM
#define KC   8192      // CODEBOOK_SIZE
#define NTOK (B_*T_)   // 16384 tokens
#define NSLICE 16
#define SLICE (KC/NSLICE)   // 512 codes per slice

// d_out layout, ALL float32: out[B,CIN,T] | indices[B,T] (as float values) | z_e[B,DD,T]
#define IDX_OFF ((size_t)B_*CIN*T_)       // 16777216
#define ZE_OFF  (IDX_OFF + NTOK)          // 16793600

// ws layout (float units) — identical footprint to the round-7 PASS (2.56 MiB)
#define WS_ENCN  0                         // 131072: normalized enc [16384][8]
#define WS_SE    (WS_ENCN + NTOK*DD)       // 16384 : sum(enc_n^2) per token
#define WS_PDIST (WS_SE + NTOK)            // 262144: partial best dist [16][16384]
#define WS_PIDX  (WS_PDIST + NSLICE*NTOK)  // 262144: partial best idx  [16][16384]

// Skewed weight-tile addressing for outproj: word W(c,d) = c*8 + 4*((c>>6)&7) + d.
__device__ __forceinline__ int wskew(int c) { return (c << 3) + (((c >> 6) & 7) << 2); }

// ---------------- Kernel 1: in-projection + normalize enc (ROUND-7 VERBATIM) ----------------
// grid = 512 blocks (NTOK/32), block = 256 threads = 8 c-groups x 32 tokens
// NOTE: the exact fmaf/add grouping here fixes the bit pattern of z_e/enc_n;
// the argmin index output is sensitive to it (round-9 post-mortem). Do not "simplify".
__global__ __launch_bounds__(256) void inproj(const float* __restrict__ z,
                                              const float* __restrict__ W_in,
                                              const float* __restrict__ b_in,
                                              float* __restrict__ out,
                                              float* __restrict__ ws) {
    __shared__ float wt[CIN * DD];        // W_in transposed to [c][d], 32 KiB
    __shared__ float red[8][32][DD];      // partial sums, 8 KiB
    int tid = threadIdx.x;
    // coalesced load of W_in [8][1024], transposed store into wt[c*8+d]
    for (int idx = tid; idx < CIN * DD; idx += 256) {
        int d = idx >> 10, c = idx & 1023;
        wt[c * 8 + d] = W_in[idx];
    }
    __syncthreads();

    int bid = blockIdx.x;
    int b  = bid >> 6;        // 64 token-groups of 32 per batch
    int tg = bid & 63;
    int t0 = tg * 32;
    int g = tid >> 5, tl = tid & 31;   // 8 c-groups x 32 tokens

    const float* zp = z + ((size_t)b * CIN) * T_ + (t0 + tl);
    float acc[8] = {0, 0, 0, 0, 0, 0, 0, 0};
    int cbeg = g * 128;
    #pragma unroll 8
    for (int c = cbeg; c < cbeg + 128; ++c) {
        float v = zp[(size_t)c * T_];
        const float4* w4 = (const float4*)&wt[c * DD];
        float4 w0 = w4[0], w1 = w4[1];
        acc[0] = fmaf(w0.x, v, acc[0]);
        acc[1] = fmaf(w0.y, v, acc[1]);
        acc[2] = fmaf(w0.z, v, acc[2]);
        acc[3] = fmaf(w0.w, v, acc[3]);
        acc[4] = fmaf(w1.x, v, acc[4]);
        acc[5] = fmaf(w1.y, v, acc[5]);
        acc[6] = fmaf(w1.z, v, acc[6]);
        acc[7] = fmaf(w1.w, v, acc[7]);
    }
    #pragma unroll
    for (int d = 0; d < 8; ++d) red[g][tl][d] = acc[d];
    __syncthreads();

    if (tid < 32) {
        int tt = tid;
        float ze[8];
        #pragma unroll
        for (int d = 0; d < 8; ++d) {
            float s01 = (red[0][tt][d] + red[1][tt][d]) + (red[2][tt][d] + red[3][tt][d]);
            float s23 = (red[4][tt][d] + red[5][tt][d]) + (red[6][tt][d] + red[7][tt][d]);
            ze[d] = (s01 + s23) + b_in[d];
        }
        // write z_e [B, 8, T]
        float* zeo = out + ZE_OFF + ((size_t)b * DD) * T_ + (t0 + tt);
        #pragma unroll
        for (int d = 0; d < 8; ++d) zeo[(size_t)d * T_] = ze[d];
        // normalize, XLA-style rounding: squares rounded individually, sequential adds
        float s2 = __fmul_rn(ze[0], ze[0]);
        #pragma unroll
        for (int d = 1; d < 8; ++d) s2 = __fadd_rn(s2, __fmul_rn(ze[d], ze[d]));
        float m = fmaxf(sqrtf(s2), 1e-12f);
        float en[8];
        #pragma unroll
        for (int d = 0; d < 8; ++d) en[d] = ze[d] / m;
        float se = __fmul_rn(en[0], en[0]);
        #pragma unroll
        for (int d = 1; d < 8; ++d) se = __fadd_rn(se, __fmul_rn(en[d], en[d]));
        int token = b * T_ + t0 + tt;
        float4* ep = (float4*)(ws + WS_ENCN + (size_t)token * DD);
        ep[0] = make_float4(en[0], en[1], en[2], en[3]);
        ep[1] = make_float4(en[4], en[5], en[6], en[7]);
        ws[WS_SE + token] = se;
    }
}

// ---------------- Kernel 2: codebook search, 2 tokens/thread ----------------
// grid = 512 = 32 token-groups(512 tok) x 16 slices; block = 256, 8 waves/CU
__global__ __launch_bounds__(256) void vq_search(const float* __restrict__ cb,
                                                 float* __restrict__ ws) {
    __shared__ float lcb[SLICE * DD];   // 16 KiB (normalized codes)
    __shared__ float lsc[SLICE];        // 2 KiB  (sum cn^2)
    int tid = threadIdx.x;
    int bid = blockIdx.x;
    int sl = bid & (NSLICE - 1);
    int tg = bid >> 4;

    // stage + normalize 512 codes (2/thread), ref-matched rounding (bitwise = round 7)
    #pragma unroll
    for (int r = 0; r < 2; ++r) {
        int jl = tid + r * 256;
        const float4* src = (const float4*)(cb + (size_t)(sl * SLICE + jl) * DD);
        float4 a = src[0], bv = src[1];
        float c[8] = {a.x, a.y, a.z, a.w, bv.x, bv.y, bv.z, bv.w};
        float s2 = __fmul_rn(c[0], c[0]);
        #pragma unroll
        for (int k = 1; k < 8; ++k) s2 = __fadd_rn(s2, __fmul_rn(c[k], c[k]));
        float m = fmaxf(sqrtf(s2), 1e-12f);
        float cn[8];
        #pragma unroll
        for (int k = 0; k < 8; ++k) cn[k] = c[k] / m;
        float sc = __fmul_rn(cn[0], cn[0]);
        #pragma unroll
        for (int k = 1; k < 8; ++k) sc = __fadd_rn(sc, __fmul_rn(cn[k], cn[k]));
        float4* dst = (float4*)&lcb[jl * DD];
        dst[0] = make_float4(cn[0], cn[1], cn[2], cn[3]);
        dst[1] = make_float4(cn[4], cn[5], cn[6], cn[7]);
        lsc[jl] = sc;
    }
    __syncthreads();

    int token0 = tg * 512 + tid * 2;
    float e[2][8], se[2];
    #pragma unroll
    for (int m = 0; m < 2; ++m) {
        const float4* ep = (const float4*)(ws + WS_ENCN + (size_t)(token0 + m) * DD);
        float4 a = ep[0], bv = ep[1];
        e[m][0] = a.x;  e[m][1] = a.y;  e[m][2] = a.z;  e[m][3] = a.w;
        e[m][4] = bv.x; e[m][5] = bv.y; e[m][6] = bv.z; e[m][7] = bv.w;
        se[m] = ws[WS_SE + token0 + m];
    }

    float best[2] = {FLT_MAX, FLT_MAX};
    int bi[2] = {0, 0};
    // dist = (se - 2*dot) + sc; identical chain + tie order to the round-7 pass
    #pragma unroll 4
    for (int j = 0; j < SLICE; ++j) {
        float4 ca = *(const float4*)&lcb[j * 8];      // uniform addr -> broadcast
        float4 cbv = *(const float4*)&lcb[j * 8 + 4];
        float sc = lsc[j];
        float cd[8] = {ca.x, ca.y, ca.z, ca.w, cbv.x, cbv.y, cbv.z, cbv.w};
        #pragma unroll
        for (int m = 0; m < 2; ++m) {
            float dot = e[m][0] * cd[0];
            #pragma unroll
            for (int k = 1; k < 8; ++k) dot = fmaf(e[m][k], cd[k], dot);
            float dist = __fadd_rn(fmaf(-2.f, dot, se[m]), sc);
            bool p = dist < best[m];                  // strict <: first min wins
            best[m] = p ? dist : best[m];
            bi[m]   = p ? j : bi[m];
        }
    }
    *(float2*)(ws + WS_PDIST + (size_t)sl * NTOK + token0) = make_float2(best[0], best[1]);
    *(int2*)((int*)ws + WS_PIDX + (size_t)sl * NTOK + token0) =
        make_int2(sl * SLICE + bi[0], sl * SLICE + bi[1]);
}

// ---------------- Kernel 3: merge + indices + gather + STE + out-projection ----------------
// grid = 256 blocks (64 tokens each); block = 256 = 16 c-groups x 16 t-quads
__global__ __launch_bounds__(256) void outproj(const float* __restrict__ ws,
                                               const float* __restrict__ cb,
                                               const float* __restrict__ W_out,
                                               const float* __restrict__ b_out,
                                               float* __restrict__ out) {
    __shared__ float wo[8224];       // skewed [c][d], ~32 KiB
    __shared__ float bo[1032];       // skewed bias
    __shared__ float zql[DD * 64];   // [d][t], 2 KiB
    int tid = threadIdx.x;
    for (int i = tid; i < CIN * DD; i += 256) {
        int c = i >> 3, d = i & 7;
        wo[wskew(c) + d] = W_out[i];
    }
    for (int i = tid; i < CIN; i += 256) bo[i + ((i >> 6) & 7)] = b_out[i];

    int bid = blockIdx.x;
    int b = bid >> 5, tg = bid & 31;
    int t0 = tg * 64;

    if (tid < 64) {
        int tl = tid;
        int token = b * T_ + t0 + tl;
        // merge 16 slice minima (strict <: earlier slice wins ties)
        float bestv = ws[WS_PDIST + token];
        int bi = ((const int*)ws)[WS_PIDX + token];
        #pragma unroll
        for (int s = 1; s < NSLICE; ++s) {
            float d = ws[WS_PDIST + (size_t)s * NTOK + token];
            int i2  = ((const int*)ws)[WS_PIDX + (size_t)s * NTOK + token];
            bool p = d < bestv;
            bestv = p ? d : bestv;
            bi    = p ? i2 : bi;
        }
        out[IDX_OFF + token] = (float)bi;   // index as float value
        // STE: z_q_out = z_e + (z_q - z_e), elementwise fp32 (bitwise = round 7)
        const float* zep = out + ZE_OFF + ((size_t)b * DD) * T_ + (t0 + tl);
        float4 ca = *(const float4*)(cb + (size_t)bi * DD);
        float4 cb2 = *(const float4*)(cb + (size_t)bi * DD + 4);
        float cv[8] = {ca.x, ca.y, ca.z, ca.w, cb2.x, cb2.y, cb2.z, cb2.w};
        #pragma unroll
        for (int d = 0; d < 8; ++d) {
            float ze = zep[(size_t)d * T_];
            zql[d * 64 + tl] = __fadd_rn(ze, __fsub_rn(cv[d], ze));
        }
    }
    __syncthreads();

    int qi = tid & 15, g = tid >> 4;
    float q[4][8];
    #pragma unroll
    for (int m = 0; m < 4; ++m)
        #pragma unroll
        for (int k = 0; k < 8; ++k) q[m][k] = zql[k * 64 + qi * 4 + m];

    float* op = out + ((size_t)b * CIN) * T_ + t0 + qi * 4;
    int cbeg = g * 64;
    int bskew = (g & 7);
    #pragma unroll 4
    for (int i = 0; i < 64; ++i) {
        int c = cbeg + i;
        int w0 = wskew(c);
        float4 wa = *(const float4*)&wo[w0];
        float4 wb = *(const float4*)&wo[w0 + 4];
        float wd[8] = {wa.x, wa.y, wa.z, wa.w, wb.x, wb.y, wb.z, wb.w};
        float bc = bo[c + bskew];
        float r[4];
        #pragma unroll
        for (int m = 0; m < 4; ++m) {
            float dot = q[m][0] * wd[0];
            #pragma unroll
            for (int k = 1; k < 8; ++k) dot = fmaf(q[m][k], wd[k], dot);
            r[m] = dot + bc;
        }
        *(float4*)(op + (size_t)c * T_) = make_float4(r[0], r[1], r[2], r[3]);  // 16 B/lane
    }
}

extern "C" void kernel_launch(void* const* d_in, const int* in_sizes, int n_in,
                              void* d_out, int out_size, void* d_ws, size_t ws_size,
                              hipStream_t stream) {
    const float* z     = (const float*)d_in[0];
    const float* W_in  = (const float*)d_in[1];
    const float* b_in  = (const float*)d_in[2];
    const float* W_out = (const float*)d_in[3];
    const float* b_out = (const float*)d_in[4];
    const float* cb    = (const float*)d_in[5];
    float* out = (float*)d_out;
    float* ws  = (float*)d_ws;

    inproj<<<NTOK / 32, 256, 0, stream>>>(z, W_in, b_in, out, ws);
    vq_search<<<(NTOK / 512) * NSLICE, 256, 0, stream>>>(cb, ws);
    outproj<<<NTOK / 64, 256, 0, stream>>>(ws, cb, W_out, b_out, out);
}